// Round 2
// baseline (149.397 us; speedup 1.0000x reference)
//
#include <hip/hip_runtime.h>
#include <hip/hip_bf16.h>
#include <math.h>

typedef __attribute__((ext_vector_type(4))) float f32x4;
typedef __attribute__((ext_vector_type(8))) short bf16x8;
typedef __attribute__((ext_vector_type(4))) int i32x4;

#define NB 2
#define NH 12
#define NS 2048
#define ND 64
#define NKER 9
#define BH (NB*NH)
#define BHS (NB*NH*NS)

using bf16 = __hip_bfloat16;

// MFMA via compiler builtin: the GCN hazard recognizer inserts the required
// wait-states around v_mfma (inline asm would NOT get them -> corrupt reads).
__device__ __forceinline__ f32x4 mfma16x16x32_bf16(bf16x8 a, bf16x8 b, f32x4 c) {
  return __builtin_amdgcn_mfma_f32_16x16x32_bf16(a, b, c, 0, 0, 0);
}

// ---------------------------------------------------------------------------
// L2-normalize Q and K rows -> bf16. One wave per 64-elem row (lane == d).
// ---------------------------------------------------------------------------
__global__ void normalize_qk(const float* __restrict__ Q, const float* __restrict__ K,
                             bf16* __restrict__ Qn, bf16* __restrict__ Kn) {
  int wid  = (blockIdx.x * blockDim.x + threadIdx.x) >> 6;
  int lane = threadIdx.x & 63;
  if (wid >= 2 * BHS) return;
  const float* src; bf16* dst; int row;
  if (wid < BHS) { src = Q; dst = Qn; row = wid; }
  else           { src = K; dst = Kn; row = wid - BHS; }
  float v  = src[(size_t)row * ND + lane];
  float ss = v * v;
  #pragma unroll
  for (int m = 1; m < 64; m <<= 1) ss += __shfl_xor(ss, m);
  float scale = 1.0f / fmaxf(sqrtf(ss), 1e-12f);
  dst[(size_t)row * ND + lane] = __float2bfloat16(v * scale);
}

// ---------------------------------------------------------------------------
// Vm^T: (V * key-mask) transposed to [BH][D][S] in bf16.
// One block per (bh, 64-row s-tile). LDS tile transpose.
// ---------------------------------------------------------------------------
__global__ void transpose_v(const float* __restrict__ V, const float* __restrict__ mask,
                            bf16* __restrict__ Vmt) {
  __shared__ bf16 tile[64][72];   // padded
  int bh = blockIdx.y;
  int b  = bh / NH;
  int s0 = blockIdx.x * 64;
  int tid = threadIdx.x;

  const float* src = V + ((size_t)bh * NS + s0) * ND;
  int r  = tid >> 2;
  int c0 = (tid & 3) * 16;
  float m = mask[b * NS + s0 + r];
  #pragma unroll
  for (int j = 0; j < 16; ++j)
    tile[r][c0 + j] = __float2bfloat16(src[(size_t)r * ND + c0 + j] * m);
  __syncthreads();

  bf16* dst = Vmt + (size_t)bh * ND * NS + s0;
  int d   = tid >> 2;
  int sc0 = (tid & 3) * 16;
  #pragma unroll
  for (int j = 0; j < 16; ++j)
    dst[(size_t)d * NS + sc0 + j] = tile[sc0 + j][d];
}

// ---------------------------------------------------------------------------
// Depthwise conv over seq axis (kernel 9), writes d_out (initialization).
// ---------------------------------------------------------------------------
__global__ void conv_kernel(const float* __restrict__ V, const float* __restrict__ mask,
                            const float* __restrict__ cw, float* __restrict__ out) {
  int idx = blockIdx.x * blockDim.x + threadIdx.x;
  if (idx >= BHS * ND) return;
  int d  = idx & (ND - 1);
  int s  = (idx >> 6) & (NS - 1);
  int bh = idx >> 17;              // ND*NS = 2^17
  int h  = bh % NH;
  int b  = bh / NH;
  float acc = 0.f;
  #pragma unroll
  for (int k = 0; k < NKER; ++k) {
    int ss = s + k - NKER / 2;
    if (ss >= 0 && ss < NS)
      acc += V[((size_t)bh * NS + ss) * ND + d] * mask[b * NS + ss] * cw[h * NKER + k];
  }
  out[idx] = acc;
}

// ---------------------------------------------------------------------------
// Fused YOSO attention: per block = 64 q-rows of one (b,h); 4 waves x 16 rows.
// Loop over 32 KV tiles of 64 keys: QK^T (MFMA) -> clip/acos/pow -> P (LDS,
// bf16) -> PV (MFMA, V^T staged). Epilogue: query mask, L2 normalize, += out.
// All LDS tiles XOR-swizzled: byte ^= (row&7)<<4.
// ---------------------------------------------------------------------------
__global__ __launch_bounds__(256) void yoso_attn(
    const bf16* __restrict__ Qn, const bf16* __restrict__ Kn,
    const bf16* __restrict__ Vmt, const float* __restrict__ mask,
    float* __restrict__ out) {
  __shared__ __align__(16) char lds[24 * 1024];
  char* kbuf = lds;                 // [64 keys][64 d] bf16, swizzled rows of 128B
  char* vbuf = lds + 8192;          // [64 d][64 keys] bf16, swizzled
  char* pbuf = lds + 16384;         // per-wave [16 q][64 keys] bf16

  int tid  = threadIdx.x;
  int wave = tid >> 6;
  int lane = tid & 63;
  int lo   = lane & 15;
  int hi   = lane >> 4;
  int bh   = blockIdx.y;
  int b    = bh / NH;
  int q0   = blockIdx.x * 64;

  const bf16* Qbh = Qn  + (size_t)bh * NS * ND;
  const bf16* Kbh = Kn  + (size_t)bh * NS * ND;
  const bf16* Vbh = Vmt + (size_t)bh * ND * NS;

  // Q fragments, held in registers for the whole kernel.
  int qrow = q0 + wave * 16 + lo;
  bf16x8 aq0 = *(const bf16x8*)(Qbh + (size_t)qrow * ND + hi * 8);
  bf16x8 aq1 = *(const bf16x8*)(Qbh + (size_t)qrow * ND + 32 + hi * 8);

  f32x4 xacc[4];
  #pragma unroll
  for (int i = 0; i < 4; ++i) xacc[i] = (f32x4){0.f, 0.f, 0.f, 0.f};

  char* pw = pbuf + wave * (16 * 128);
  const float inv_pi = 0.3183098861837907f;

  for (int kt = 0; kt < NS / 64; ++kt) {
    __syncthreads();   // previous tile fully consumed before overwrite
    // Stage K tile and V^T tile: 512 x 16B chunks each, 2 per thread each.
    #pragma unroll
    for (int it = 0; it < 2; ++it) {
      int c    = tid + it * 256;
      int row  = c >> 3;
      int coff = (c & 7) * 16;
      int sw   = (row & 7) << 4;
      i32x4 kd = *(const i32x4*)((const char*)(Kbh + (size_t)(kt * 64 + row) * ND) + coff);
      *(i32x4*)(kbuf + row * 128 + (coff ^ sw)) = kd;
      i32x4 vd = *(const i32x4*)((const char*)(Vbh + (size_t)row * NS + kt * 64) + coff);
      *(i32x4*)(vbuf + row * 128 + (coff ^ sw)) = vd;
    }
    __syncthreads();

    // QK^T per 16-key column group, then weight transform, store P.
    #pragma unroll
    for (int cg = 0; cg < 4; ++cg) {
      f32x4 s = (f32x4){0.f, 0.f, 0.f, 0.f};
      int krow = cg * 16 + lo;
      const char* kbase = kbuf + krow * 128;
      int sw = (krow & 7) << 4;
      bf16x8 bk0 = *(const bf16x8*)(kbase + ((hi * 16) ^ sw));
      bf16x8 bk1 = *(const bf16x8*)(kbase + ((64 + hi * 16) ^ sw));
      s = mfma16x16x32_bf16(aq0, bk0, s);
      s = mfma16x16x32_bf16(aq1, bk1, s);
      #pragma unroll
      for (int r = 0; r < 4; ++r) {
        float qk = fminf(fmaxf(s[r], -1.0f + 1e-6f), 1.0f - 1e-6f);
        float t  = 1.0f - acosf(qk) * inv_pi;
        float t2 = t * t, t4 = t2 * t2, w = t4 * t4;
        int prow = hi * 4 + r;
        int pcol = cg * 16 + lo;
        *(bf16*)(pw + prow * 128 + ((pcol * 2) ^ ((prow & 7) << 4))) = __float2bfloat16(w);
      }
    }

    // PV: X += P @ Vm  (K-dim = keys, 2 steps of 32).
    #pragma unroll
    for (int ks = 0; ks < 2; ++ks) {
      const char* pbase = pw + lo * 128;
      bf16x8 ap = *(const bf16x8*)(pbase + ((ks * 64 + hi * 16) ^ ((lo & 7) << 4)));
      #pragma unroll
      for (int dg = 0; dg < 4; ++dg) {
        int drow = dg * 16 + lo;
        const char* vbase = vbuf + drow * 128;
        bf16x8 bv = *(const bf16x8*)(vbase + ((ks * 64 + hi * 16) ^ ((drow & 7) << 4)));
        xacc[dg] = mfma16x16x32_bf16(ap, bv, xacc[dg]);
      }
    }
  }

  // Epilogue: query-side mask, L2 normalize per q-row, accumulate into out.
  #pragma unroll
  for (int r = 0; r < 4; ++r) {
    int row = q0 + wave * 16 + hi * 4 + r;
    float m = mask[b * NS + row];
    float vals[4];
    float ss = 0.f;
    #pragma unroll
    for (int dg = 0; dg < 4; ++dg) {
      float x = xacc[dg][r] * m;
      vals[dg] = x;
      ss += x * x;
    }
    #pragma unroll
    for (int mm = 1; mm < 16; mm <<= 1) ss += __shfl_xor(ss, mm);
    float scale = 1.0f / fmaxf(sqrtf(ss), 1e-12f);
    size_t base = ((size_t)bh * NS + row) * ND;
    #pragma unroll
    for (int dg = 0; dg < 4; ++dg) {
      int d = dg * 16 + lo;
      out[base + d] += vals[dg] * scale;
    }
  }
}

// ---------------------------------------------------------------------------
extern "C" void kernel_launch(void* const* d_in, const int* in_sizes, int n_in,
                              void* d_out, int out_size, void* d_ws, size_t ws_size,
                              hipStream_t stream) {
  const float* Q    = (const float*)d_in[0];
  const float* K    = (const float*)d_in[1];
  const float* V    = (const float*)d_in[2];
  const float* mask = (const float*)d_in[3];
  const float* cw   = (const float*)d_in[4];
  float* out = (float*)d_out;

  bf16* Qn  = (bf16*)d_ws;
  bf16* Kn  = Qn + (size_t)BHS * ND;
  bf16* Vmt = Kn + (size_t)BHS * ND;

  // 2*BHS rows, one wave each, 4 waves per block.
  normalize_qk<<<2 * BHS / 4, 256, 0, stream>>>(Q, K, Qn, Kn);
  transpose_v<<<dim3(NS / 64, BH), 256, 0, stream>>>(V, mask, Vmt);
  conv_kernel<<<(BHS * ND + 255) / 256, 256, 0, stream>>>(V, mask, cw, out);
  yoso_attn<<<dim3(NS / 64, BH), 256, 0, stream>>>(Qn, Kn, Vmt, mask, out);
}